// Round 10
// baseline (48.837 us; speedup 1.0000x reference)
//
#include <hip/hip_runtime.h>
#include <math.h>

#define N_T   16384
#define BLOCK 256
#define CHSZ  4096        // own chunk per block
#define SUB   1024        // elements per sub-chunk iteration (BLOCK*4)
#define NSUB  4           // sub-chunks per chunk
#define NWAVE 4
#define CPR   4           // chunks per row

// MODE 0: d_out = real part only, flat (16,64,16384) float32  (out_size = N)
// MODE 1: d_out = interleaved re/im pairs                     (out_size = 2N)
template <int MODE>
__global__ __launch_bounds__(BLOCK)
void phase_kernel(const float* __restrict__ x, float* __restrict__ out,
                  int n_rows) {
    __shared__ float rawEdge[NSUB][NWAVE];
    __shared__ int   wtot[NSUB][NWAVE];
    __shared__ float corrR[NSUB][NWAVE];
    __shared__ float corrL[NSUB][NWAVE];
    __shared__ int   preSum[NWAVE];

    const int tid  = threadIdx.x;
    const int lane = tid & 63;
    const int wv   = tid >> 6;
    const int bid  = blockIdx.x;
    // row = bid % n_rows, cpos = bid / n_rows  (keeps a row's 4 blocks on one XCD)
    int cpos = 0;
    {
        int t = bid;
        if (t >= 2 * n_rows) { cpos += 2; t -= 2 * n_rows; }
        if (t >= n_rows)     { cpos += 1; t -= n_rows; }
    }
    const int row = bid - cpos * n_rows;
    const int b   = row >> 6;
    const int c   = row & 63;
    const float* __restrict__ row_ph   = x + ((size_t)(b * 128 + 64 + c)) * N_T;
    const float* __restrict__ chunk_ph = row_ph + cpos * CHSZ;
    const float* __restrict__ chunk_mg = x + ((size_t)(b * 128 + c)) * N_T + cpos * CHSZ;

    const float TWO_PI = 6.28318530717958647692f;  // f32 0x40C90FDB
    const float PI_F   = 3.14159265358979323846f;
    const float THIRD  = 1.0f / 3.0f;

    // ---- 0. own-chunk loads first (critical path), coalesced float4
    float s[16];
    #pragma unroll
    for (int i = 0; i < NSUB; ++i) {
        float4 v = *reinterpret_cast<const float4*>(chunk_ph + i * SUB + tid * 4);
        s[i * 4 + 0] = v.x; s[i * 4 + 1] = v.y;
        s[i * 4 + 2] = v.z; s[i * 4 + 3] = v.w;
    }
    // boundary raw values (single-lane scalar loads, prefetched)
    float leftRaw = 0.0f, leftRaw2 = 0.0f, rightRaw = 0.0f;
    if (tid == 0 && cpos > 0)        { leftRaw = chunk_ph[-1]; leftRaw2 = chunk_ph[-2]; }
    if (tid == BLOCK - 1 && cpos < CPR - 1) rightRaw = chunk_ph[CHSZ];

    // ---- A. jump-count of preceding chunks [0, cpos*CHSZ)  (order-independent)
    if (cpos > 0) {
        const int L     = cpos * SUB;      // per-wave range length
        const int start = wv * L;
        float carry = 0.0f;
        if (lane == 0 && start > 0) carry = row_ph[start - 1];
        carry = __shfl(carry, 0);
        const bool first0 = (start == 0);
        int cnt = 0;
        for (int it = 0; it < cpos * 4; ++it) {
            float4 v = *reinterpret_cast<const float4*>(row_ph + start + it * 256 + lane * 4);
            float up   = __shfl_up(v.w, 1);
            float prev = (lane == 0) ? carry : up;
            float g0 = v.x - prev, g1 = v.y - v.x, g2 = v.z - v.y, g3 = v.w - v.z;
            bool first = first0 && it == 0 && lane == 0;   // row elem 0: d=0
            if (!first && fabsf(g0) > 0.5f) cnt += (g0 > 0.0f) ? 1 : -1;
            if (fabsf(g1) > 0.5f)           cnt += (g1 > 0.0f) ? 1 : -1;
            if (fabsf(g2) > 0.5f)           cnt += (g2 > 0.0f) ? 1 : -1;
            if (fabsf(g3) > 0.5f)           cnt += (g3 > 0.0f) ? 1 : -1;
            carry = __shfl(v.w, 63);
        }
        #pragma unroll
        for (int off = 32; off; off >>= 1) cnt += __shfl_xor(cnt, off);
        if (lane == 0) preSum[wv] = cnt;
    }

    // publish raw sub-chunk edge values (lane63's .w)
    if (lane == 63) {
        #pragma unroll
        for (int i = 0; i < NSUB; ++i) rawEdge[i][wv] = s[i * 4 + 3];
    }
    __syncthreads();                                   // barrier A

    int pre = 0;
    if (cpos > 0) pre = preSum[0] + preSum[1] + preSum[2] + preSum[3];

    // raw element just before each sub-chunk segment of this thread
    float prevRaw[NSUB];
    #pragma unroll
    for (int i = 0; i < NSUB; ++i) {
        float p = __shfl_up(s[i * 4 + 3], 1);
        if (lane == 0) {
            if (wv > 0)      p = rawEdge[i][wv - 1];
            else if (i > 0)  p = rawEdge[i - 1][NWAVE - 1];
            else             p = leftRaw;              // 0.0f when cpos==0 (d[0]=0 anyway)
        }
        prevRaw[i] = p;
    }

    // ---- 2. per-sub-chunk local jump-counts
    int lsum[NSUB];
    #pragma unroll
    for (int i = 0; i < NSUB; ++i) {
        float prev = prevRaw[i];
        int cnt = 0;
        #pragma unroll
        for (int k = 0; k < 4; ++k) {
            float cur = s[i * 4 + k];
            float g = cur - prev;
            bool first = (cpos == 0 && i == 0 && tid == 0 && k == 0);
            if (!first && fabsf(g) > 0.5f) cnt += (g > 0.0f) ? 1 : -1;
            prev = cur;
        }
        lsum[i] = cnt;
    }

    // ---- 3. parallel wave scans + cross-wave/sub-chunk prefix
    int incl[NSUB] = {lsum[0], lsum[1], lsum[2], lsum[3]};
    #pragma unroll
    for (int off = 1; off < 64; off <<= 1) {
        #pragma unroll
        for (int i = 0; i < NSUB; ++i) {
            int n = __shfl_up(incl[i], off);
            if (lane >= off) incl[i] += n;
        }
    }
    if (lane == 63) {
        #pragma unroll
        for (int i = 0; i < NSUB; ++i) wtot[i][wv] = incl[i];
    }
    __syncthreads();                                   // barrier B

    int P[NSUB];
    int chunkPre = pre;
    #pragma unroll
    for (int i = 0; i < NSUB; ++i) {
        int wpre = 0, tot = 0;
        #pragma unroll
        for (int w = 0; w < NWAVE; ++w) {
            int t = wtot[i][w];                        // wave-uniform broadcast
            if (w < wv) wpre += t;
            tot += t;
        }
        P[i] = chunkPre + wpre + (incl[i] - lsum[i]);  // exclusive prefix
        chunkPre += tot;
    }
    // chunkPre == pre + S_own (uniform across block)

    // ---- 4. corrected phase in place
    #pragma unroll
    for (int i = 0; i < NSUB; ++i) {
        int running = P[i];
        float prev = prevRaw[i];
        #pragma unroll
        for (int k = 0; k < 4; ++k) {
            float cur = s[i * 4 + k];
            int d = 0;
            bool first = (cpos == 0 && i == 0 && tid == 0 && k == 0);
            if (!first) {
                float g = cur - prev;
                if (fabsf(g) > 0.5f) d = (g > 0.0f) ? 1 : -1;
            }
            s[i * 4 + k] = (cur - (float)running) * TWO_PI - PI_F;
            running += d;
            prev = cur;
        }
    }

    // chunk-edge corrected neighbors (exact recompute from raw + int corr)
    float v_left = 0.0f, v_right = 0.0f;
    if (tid == 0 && cpos > 0) {
        float g = leftRaw - leftRaw2;
        int d = (fabsf(g) > 0.5f) ? ((g > 0.0f) ? 1 : -1) : 0;
        int corr = pre - d;                            // corr[cL-1]
        v_left = (leftRaw - (float)corr) * TWO_PI - PI_F;
    }
    if (tid == BLOCK - 1 && cpos < CPR - 1) {
        int corr = chunkPre;                           // corr[(c+1)L] = pre + S_own
        v_right = (rightRaw - (float)corr) * TWO_PI - PI_F;
    }

    // publish corrected edges; mag loads issued here (R7's winning placement)
    if (lane == 63) {
        #pragma unroll
        for (int i = 0; i < NSUB; ++i) corrR[i][wv] = s[i * 4 + 3];
    }
    if (lane == 0) {
        #pragma unroll
        for (int i = 0; i < NSUB; ++i) corrL[i][wv] = s[i * 4 + 0];
    }
    float4 mg[NSUB];
    #pragma unroll
    for (int i = 0; i < NSUB; ++i)
        mg[i] = *reinterpret_cast<const float4*>(chunk_mg + i * SUB + tid * 4);
    __syncthreads();                                   // barrier C

    // ---- 5. smooth + blend + range-reduced cos/sin + coalesced store
    #pragma unroll
    for (int i = 0; i < NSUB; ++i) {
        float left = __shfl_up(s[i * 4 + 3], 1);
        if (lane == 0) {
            if (wv > 0)      left = corrR[i][wv - 1];
            else if (i > 0)  left = corrR[i - 1][NWAVE - 1];
            else             left = v_left;            // 0 at row start
        }
        float right = __shfl_down(s[i * 4 + 0], 1);
        if (lane == 63) {
            if (wv < NWAVE - 1)   right = corrL[i][wv + 1];
            else if (i < NSUB - 1) right = corrL[i + 1][0];
            else                   right = v_right;    // 0 at row end
        }

        float mgk[4] = {mg[i].x, mg[i].y, mg[i].z, mg[i].w};
        float re[4], im[4];
        #pragma unroll
        for (int k = 0; k < 4; ++k) {
            float pm = (k == 0) ? left  : s[i * 4 + k - 1];
            float pp = (k == 3) ? right : s[i * 4 + k + 1];
            float cur = s[i * 4 + k];
            float sm = ((pm + cur) + pp) * THIRD;
            float pf = 0.7f * cur + 0.3f * sm;
            // two-term range reduction: 2pi = hi + lo
            float nrev = rintf(pf * 0.15915494309189535f);
            float rr = fmaf(nrev, -6.28318548202514648f, pf);
            rr = fmaf(nrev, 1.74845553e-7f, rr);
            re[k] = mgk[k] * __cosf(rr);
            if (MODE == 1) im[k] = mgk[k] * __sinf(rr);
        }
        if (MODE == 0) {
            float* o = out + (size_t)row * N_T + cpos * CHSZ + i * SUB + tid * 4;
            *reinterpret_cast<float4*>(o) = make_float4(re[0], re[1], re[2], re[3]);
        } else {
            float* o = out + (size_t)row * (2 * N_T) + 2 * (cpos * CHSZ + i * SUB + tid * 4);
            *reinterpret_cast<float4*>(o)     = make_float4(re[0], im[0], re[1], im[1]);
            *reinterpret_cast<float4*>(o + 4) = make_float4(re[2], im[2], re[3], im[3]);
        }
    }
}

extern "C" void kernel_launch(void* const* d_in, const int* in_sizes, int n_in,
                              void* d_out, int out_size, void* d_ws, size_t ws_size,
                              hipStream_t stream) {
    const float* x = (const float*)d_in[0];
    float* out = (float*)d_out;
    int n_rows = in_sizes[0] / (2 * N_T);              // 1024
    int grid = n_rows * CPR;                           // 4096 blocks
    if (out_size >= in_sizes[0]) {
        phase_kernel<1><<<grid, BLOCK, 0, stream>>>(x, out, n_rows);
    } else {
        phase_kernel<0><<<grid, BLOCK, 0, stream>>>(x, out, n_rows);
    }
}

// Round 11
// 36.521 us; speedup vs baseline: 1.3372x; 1.3372x over previous
//
#include <hip/hip_runtime.h>
#include <math.h>

#define N_T    16384
#define BLOCK  1024
#define NCH    4          // chunks per row; chunk = 4096 elems
#define CHSZ   4096
#define NWAVE  16

// MODE 0: d_out = real part only, flat (16,64,16384) float32  (out_size = N)
// MODE 1: d_out = interleaved re/im pairs                     (out_size = 2N)
template <int MODE>
__global__ __launch_bounds__(BLOCK)
void phase_kernel(const float* __restrict__ x, float* __restrict__ out) {
    // 1 KiB of LDS total — occupancy limited only by VGPRs
    __shared__ float rawEdge[NCH][NWAVE];  // raw .w of lane63, per chunk/wave
    __shared__ int   wtot[NCH][NWAVE];     // wave-inclusive jump totals
    __shared__ float corrR[NCH][NWAVE];    // corrected .w of lane63
    __shared__ float corrL[NCH][NWAVE];    // corrected .x of lane0

    const int tid  = threadIdx.x;
    const int lane = tid & 63;
    const int wv   = tid >> 6;
    const int r    = blockIdx.x;          // row in [0, 1024)
    const int b    = r >> 6;
    const int c    = r & 63;
    const float* __restrict__ phase_row = x + ((size_t)(b * 128 + 64 + c)) * N_T;
    const float* __restrict__ mag_row   = x + ((size_t)(b * 128 + c)) * N_T;

    const float TWO_PI = 6.28318530717958647692f;  // f32 0x40C90FDB
    const float PI_F   = 3.14159265358979323846f;
    const float THIRD  = 1.0f / 3.0f;

    // ---- 1. coalesced register load: chunk i, elements i*4096 + tid*4 .. +3
    float s[16];
    #pragma unroll
    for (int i = 0; i < NCH; ++i) {
        float4 v = *reinterpret_cast<const float4*>(phase_row + i * CHSZ + tid * 4);
        s[i * 4 + 0] = v.x; s[i * 4 + 1] = v.y;
        s[i * 4 + 2] = v.z; s[i * 4 + 3] = v.w;
    }

    // publish raw wave-edge values (lane63's .w per chunk)
    if (lane == 63) {
        #pragma unroll
        for (int i = 0; i < NCH; ++i) rawEdge[i][wv] = s[i * 4 + 3];
    }
    __syncthreads();                                   // barrier A

    // raw element just before each chunk-segment of this thread
    float prevRaw[NCH];
    #pragma unroll
    for (int i = 0; i < NCH; ++i) {
        float p = __shfl_up(s[i * 4 + 3], 1);
        if (lane == 0) {
            if (wv > 0)      p = rawEdge[i][wv - 1];
            else if (i > 0)  p = rawEdge[i - 1][NWAVE - 1];
            else             p = 0.0f;                 // t==0: d forced 0 below
        }
        prevRaw[i] = p;
    }

    // ---- 2. per-chunk local jump-counts (4 elements each)
    int lsum[NCH];
    #pragma unroll
    for (int i = 0; i < NCH; ++i) {
        float prev = prevRaw[i];
        int cnt = 0;
        #pragma unroll
        for (int k = 0; k < 4; ++k) {
            float cur = s[i * 4 + k];
            float g = cur - prev;
            bool first = (i == 0 && tid == 0 && k == 0);
            if (!first && fabsf(g) > 0.5f) cnt += (g > 0.0f) ? 1 : -1;
            prev = cur;
        }
        lsum[i] = cnt;
    }

    // ---- 3. four parallel wave-inclusive scans, then cross-wave/chunk prefix
    int incl[NCH] = {lsum[0], lsum[1], lsum[2], lsum[3]};
    #pragma unroll
    for (int off = 1; off < 64; off <<= 1) {
        #pragma unroll
        for (int i = 0; i < NCH; ++i) {
            int n = __shfl_up(incl[i], off);
            if (lane >= off) incl[i] += n;
        }
    }
    if (lane == 63) {
        #pragma unroll
        for (int i = 0; i < NCH; ++i) wtot[i][wv] = incl[i];
    }
    __syncthreads();                                   // barrier B

    int P[NCH];
    {
        int chunkPre = 0;
        #pragma unroll
        for (int i = 0; i < NCH; ++i) {
            int wpre = 0, tot = 0;
            #pragma unroll
            for (int w = 0; w < NWAVE; ++w) {
                int t = wtot[i][w];                    // wave-uniform broadcast
                if (w < wv) wpre += t;
                tot += t;
            }
            P[i] = chunkPre + wpre + (incl[i] - lsum[i]);  // exclusive prefix
            chunkPre += tot;
        }
    }

    // ---- 4. corrected phase in place
    #pragma unroll
    for (int i = 0; i < NCH; ++i) {
        int running = P[i];
        float prev = prevRaw[i];
        #pragma unroll
        for (int k = 0; k < 4; ++k) {
            float cur = s[i * 4 + k];
            int d = 0;
            bool first = (i == 0 && tid == 0 && k == 0);
            if (!first) {
                float g = cur - prev;
                if (fabsf(g) > 0.5f) d = (g > 0.0f) ? 1 : -1;
            }
            s[i * 4 + k] = (cur - (float)running) * TWO_PI - PI_F;
            running += d;
            prev = cur;
        }
    }

    // publish corrected edges
    if (lane == 63) {
        #pragma unroll
        for (int i = 0; i < NCH; ++i) corrR[i][wv] = s[i * 4 + 3];
    }
    if (lane == 0) {
        #pragma unroll
        for (int i = 0; i < NCH; ++i) corrL[i][wv] = s[i * 4 + 0];
    }
    __syncthreads();                                   // barrier C (last barrier)

    // ---- mag loads AFTER the last barrier: no __syncthreads ever drains
    //      them; the only wait is the compiler's counted vmcnt before each
    //      mg[i]'s first use — which is the FINAL multiply of chunk i, so
    //      the whole edge-shuffle + smooth + range-reduce + v_cos chain of
    //      chunks 0..i covers the flight time. Mag needs no barrier: it has
    //      no cross-thread exchange.
    float4 mg[NCH];
    #pragma unroll
    for (int i = 0; i < NCH; ++i)
        mg[i] = *reinterpret_cast<const float4*>(mag_row + i * CHSZ + tid * 4);

    // ---- 5. smooth + blend + range-reduced cos/sin + coalesced store
    #pragma unroll
    for (int i = 0; i < NCH; ++i) {
        float left = __shfl_up(s[i * 4 + 3], 1);
        if (lane == 0) {
            if (wv > 0)      left = corrR[i][wv - 1];
            else if (i > 0)  left = corrR[i - 1][NWAVE - 1];
            else             left = 0.0f;              // zero pad at t==0
        }
        float right = __shfl_down(s[i * 4 + 0], 1);
        if (lane == 63) {
            if (wv < NWAVE - 1)  right = corrL[i][wv + 1];
            else if (i < NCH - 1) right = corrL[i + 1][0];
            else                  right = 0.0f;        // zero pad at t==N-1
        }

        float re[4], im[4];
        #pragma unroll
        for (int k = 0; k < 4; ++k) {
            float pm = (k == 0) ? left  : s[i * 4 + k - 1];
            float pp = (k == 3) ? right : s[i * 4 + k + 1];
            float cur = s[i * 4 + k];
            float sm = ((pm + cur) + pp) * THIRD;
            float pf = 0.7f * cur + 0.3f * sm;
            // two-term range reduction: 2pi = hi + lo
            float nrev = rintf(pf * 0.15915494309189535f);
            float rr = fmaf(nrev, -6.28318548202514648f, pf);
            rr = fmaf(nrev, 1.74845553e-7f, rr);
            float cs = __cosf(rr);
            float mgk = (k == 0) ? mg[i].x : (k == 1) ? mg[i].y
                       : (k == 2) ? mg[i].z : mg[i].w;
            re[k] = mgk * cs;
            if (MODE == 1) im[k] = mgk * __sinf(rr);
        }
        if (MODE == 0) {
            float* o = out + (size_t)r * N_T + i * CHSZ + tid * 4;
            *reinterpret_cast<float4*>(o) = make_float4(re[0], re[1], re[2], re[3]);
        } else {
            float* o = out + (size_t)r * (2 * N_T) + 2 * (i * CHSZ + tid * 4);
            *reinterpret_cast<float4*>(o)     = make_float4(re[0], im[0], re[1], im[1]);
            *reinterpret_cast<float4*>(o + 4) = make_float4(re[2], im[2], re[3], im[3]);
        }
    }
}

extern "C" void kernel_launch(void* const* d_in, const int* in_sizes, int n_in,
                              void* d_out, int out_size, void* d_ws, size_t ws_size,
                              hipStream_t stream) {
    const float* x = (const float*)d_in[0];
    float* out = (float*)d_out;
    int n_rows = in_sizes[0] / (2 * N_T);              // 1024
    if (out_size >= in_sizes[0]) {
        phase_kernel<1><<<n_rows, BLOCK, 0, stream>>>(x, out);
    } else {
        phase_kernel<0><<<n_rows, BLOCK, 0, stream>>>(x, out);
    }
}